// Round 8
// baseline (21.500 us; speedup 1.0000x reference)
//
#include <hip/hip_runtime.h>
#include <math.h>

#define L 512
#define TILE_T 16
#define NTHREADS 256
#define CHUNK 64
#define ZWIN 9.0f        // dropped pdf mass <= exp(-40.5): < 1e-10 effect on output
#define NXCD 8

static constexpr float EPS = 1e-6f;
static constexpr float INV_SQRT_2PI = 0.39894228040143267794f;

__global__ __launch_bounds__(NTHREADS, 8) void ge_kernel(
    const float* __restrict__ text,  // [B, L, D]
    const int*   __restrict__ durs,  // [B, L]
    float*       __restrict__ out,   // [B, T, D]
    int B, int D, int T, int tilesPerB, int nwg)
{
    __shared__ float2 s_mi[L];            // (mean, 1/sigma) — every wave writes ALL entries
    __shared__ float4 s_p[4][CHUNK];      // per-wave packed probs [item] -> (p_t0..p_t3)

    const int tid  = threadIdx.x;
    const int lane = tid & 63;
    const int wid  = tid >> 6;

    // XCD-aware bijective swizzle (nwg % NXCD == 0)
    const int orig = blockIdx.x;
    const int wg   = (orig & (NXCD - 1)) * (nwg / NXCD) + (orig >> 3);
    const int b    = wg / tilesPerB;
    const int t0   = (wg % tilesPerB) * TILE_T;

    // ---- wave-private full cumsum: lane owns rows 8*lane..8*lane+7 ----
    const int r0 = lane << 3;
    const int4* dp = (const int4*)(durs + (size_t)b * L + r0);
    const int4 da = dp[0];
    const int4 db = dp[1];
    int dv[8] = {da.x, da.y, da.z, da.w, db.x, db.y, db.z, db.w};
    int csum[8];
    {
        int run = 0;
        #pragma unroll
        for (int j = 0; j < 8; ++j) { run += dv[j]; csum[j] = run; }
        int v = run;
        #pragma unroll
        for (int off = 1; off < 64; off <<= 1) {
            int n = __shfl_up(v, off, 64);
            if (lane >= off) v += n;
        }
        const int excl = v - run;
        #pragma unroll
        for (int j = 0; j < 8; ++j) csum[j] += excl;   // inclusive cumsum
    }

    const float tlo = (float)t0 + 0.5f;
    const float thi = (float)t0 + (float)TILE_T - 0.5f;

    // ---- params to LDS + active-band min/max (contiguous band, no compaction) ----
    int myMin = L, myMax = -1;
    #pragma unroll
    for (int j = 0; j < 8; ++j) {
        const float d  = (float)dv[j];
        const float m  = (float)csum[j] + 0.5f * d;    // cumsum_incl + d/2
        const float sg = 0.5f * d + EPS;
        s_mi[r0 + j] = make_float2(m, 1.0f / sg);
        const float r = ZWIN * sg;
        if ((dv[j] >= 1) && (m + r >= tlo) && (m - r <= thi)) {
            myMin = min(myMin, r0 + j);
            myMax = max(myMax, r0 + j);
        }
    }
    #pragma unroll
    for (int off = 32; off > 0; off >>= 1) {
        myMin = min(myMin, __shfl_xor(myMin, off, 64));
        myMax = max(myMax, __shfl_xor(myMax, off, 64));
    }
    // this wave wrote every s_mi entry itself -> wave-local fence suffices (no __syncthreads)
    asm volatile("s_waitcnt lgkmcnt(0)" ::: "memory");
    __builtin_amdgcn_sched_barrier(0);

    // ---- band sweep: probs (4 t's per wave) then streaming affine FMA loop ----
    const float tq = (float)(t0 + (wid << 2)) + 0.5f;
    float ps0 = 0.f, ps1 = 0.f, ps2 = 0.f, ps3 = 0.f;
    float4 a0 = {0,0,0,0}, a1 = {0,0,0,0}, a2 = {0,0,0,0}, a3 = {0,0,0,0};
    const float* tb = text + (size_t)b * L * D + (lane << 2);

    for (int cbase = myMin; cbase <= myMax; cbase += CHUNK) {
        const int nb = min(CHUNK, myMax - cbase + 1);

        float4 pv = {0.f, 0.f, 0.f, 0.f};
        if (lane < nb) {
            const float2 mi = s_mi[cbase + lane];
            const float c  = mi.y * INV_SQRT_2PI;
            const float z0 = (tq + 0.f - mi.x) * mi.y;
            const float z1 = (tq + 1.f - mi.x) * mi.y;
            const float z2 = (tq + 2.f - mi.x) * mi.y;
            const float z3 = (tq + 3.f - mi.x) * mi.y;
            pv.x = __expf(-0.5f * z0 * z0) * c;
            pv.y = __expf(-0.5f * z1 * z1) * c;
            pv.z = __expf(-0.5f * z2 * z2) * c;
            pv.w = __expf(-0.5f * z3 * z3) * c;
            ps0 += pv.x; ps1 += pv.y; ps2 += pv.z; ps3 += pv.w;
        }
        s_p[wid][lane] = pv;                          // all 64 entries written (zeros past nb)
        asm volatile("s_waitcnt lgkmcnt(0)" ::: "memory");
        __builtin_amdgcn_sched_barrier(0);

        const int nbr = (nb + 3) & ~3;                // probs are 0-padded to 64
        for (int i = 0; i < nbr; i += 4) {
            #pragma unroll
            for (int k = 0; k < 4; ++k) {
                const int row = min(cbase + i + k, L - 1);   // clamp pad rows (p==0 anyway)
                const float4 val = *(const float4*)(tb + (size_t)row * D);
                const float4 p   = s_p[wid][i + k];          // wave-uniform broadcast b128
                a0.x += p.x*val.x; a0.y += p.x*val.y; a0.z += p.x*val.z; a0.w += p.x*val.w;
                a1.x += p.y*val.x; a1.y += p.y*val.y; a1.z += p.y*val.z; a1.w += p.y*val.w;
                a2.x += p.z*val.x; a2.y += p.z*val.y; a2.z += p.z*val.z; a2.w += p.z*val.w;
                a3.x += p.w*val.x; a3.y += p.w*val.y; a3.z += p.w*val.z; a3.w += p.w*val.w;
            }
        }
        // WAR fence before next chunk overwrites s_p (multi-chunk is rare)
        asm volatile("s_waitcnt lgkmcnt(0)" ::: "memory");
        __builtin_amdgcn_sched_barrier(0);
    }

    // ---- denominators (in-wave reduce) + normalize + store ----
    #pragma unroll
    for (int off = 32; off > 0; off >>= 1) {
        ps0 += __shfl_xor(ps0, off, 64);
        ps1 += __shfl_xor(ps1, off, 64);
        ps2 += __shfl_xor(ps2, off, 64);
        ps3 += __shfl_xor(ps3, off, 64);
    }
    const float rn0 = 1.0f / (ps0 + EPS);
    const float rn1 = 1.0f / (ps1 + EPS);
    const float rn2 = 1.0f / (ps2 + EPS);
    const float rn3 = 1.0f / (ps3 + EPS);

    const int ttq = t0 + (wid << 2);
    float* ob = out + ((size_t)b * T + ttq) * D + (lane << 2);
    if (ttq + 0 < T) *(float4*)(ob + 0*(size_t)D) = make_float4(a0.x*rn0, a0.y*rn0, a0.z*rn0, a0.w*rn0);
    if (ttq + 1 < T) *(float4*)(ob + 1*(size_t)D) = make_float4(a1.x*rn1, a1.y*rn1, a1.z*rn1, a1.w*rn1);
    if (ttq + 2 < T) *(float4*)(ob + 2*(size_t)D) = make_float4(a2.x*rn2, a2.y*rn2, a2.z*rn2, a2.w*rn2);
    if (ttq + 3 < T) *(float4*)(ob + 3*(size_t)D) = make_float4(a3.x*rn3, a3.y*rn3, a3.z*rn3, a3.w*rn3);
}

extern "C" void kernel_launch(void* const* d_in, const int* in_sizes, int n_in,
                              void* d_out, int out_size, void* d_ws, size_t ws_size,
                              hipStream_t stream) {
    const float* text = (const float*)d_in[0];
    const int*   durs = (const int*)d_in[1];
    float*       out  = (float*)d_out;

    const int BL = in_sizes[1];        // B * L
    const int D  = in_sizes[0] / BL;   // 256
    const int B  = BL / L;             // 16
    const int T  = out_size / (B * D); // 2048
    const int tilesPerB = (T + TILE_T - 1) / TILE_T;
    const int nwg = B * tilesPerB;     // 2048, divisible by 8

    ge_kernel<<<dim3(nwg), dim3(NTHREADS), 0, stream>>>(
        text, durs, out, B, D, T, tilesPerB, nwg);
}